// Round 2
// baseline (530.805 us; speedup 1.0000x reference)
//
#include <hip/hip_runtime.h>

#define D_ORIENT 12
#define HW 16384                 // 128*128
#define TB 256
#define NCHUNK 8                 // copy-kernel chunks per (b,c)

// Kernel A: one block per (b,c,d) slice of HW floats -> slice max.
// Pure value reduction (no index): the winner only needs the orientation d,
// and cross-slice ties resolve to the smallest d in kernel B (strict >),
// matching jnp.argmax first-occurrence semantics.
__global__ __launch_bounds__(TB) void k_slicemax(const float* __restrict__ x,
                                                 float* __restrict__ pval) {
    const int s = blockIdx.x;                         // (b,c,d) slice id
    const float4* __restrict__ src4 = (const float4*)(x + (size_t)s * HW);
    const int tid = threadIdx.x;

    float best = -__builtin_inff();
    // 4096 float4 / 256 threads = 16 iterations; full unroll -> 16 loads in flight
    #pragma unroll
    for (int i = tid; i < HW / 4; i += TB) {
        float4 v = src4[i];
        best = fmaxf(best, fmaxf(fmaxf(v.x, v.y), fmaxf(v.z, v.w)));
    }

    // wave-64 shuffle max
    #pragma unroll
    for (int off = 32; off >= 1; off >>= 1)
        best = fmaxf(best, __shfl_down(best, off, 64));

    __shared__ float sv[TB / 64];
    if ((tid & 63) == 0) sv[tid >> 6] = best;
    __syncthreads();
    if (tid == 0) {
        float b = sv[0];
        #pragma unroll
        for (int w = 1; w < TB / 64; ++w) b = fmaxf(b, sv[w]);
        pval[s] = b;
    }
}

// Kernel B: one block per (b,c)-chunk. Re-derives the winning d from the 12
// partial maxima (L2-hot), then copies its chunk of the winning slice.
__global__ __launch_bounds__(TB) void k_copy(const float* __restrict__ x,
                                             const float* __restrict__ pval,
                                             float* __restrict__ out) {
    const int bc    = blockIdx.x / NCHUNK;
    const int chunk = blockIdx.x % NCHUNK;
    const int tid   = threadIdx.x;

    __shared__ float sv[D_ORIENT];
    __shared__ int s_d;
    if (tid < D_ORIENT) sv[tid] = pval[bc * D_ORIENT + tid];
    __syncthreads();
    if (tid == 0) {
        float bv = sv[0];
        int bd = 0;
        #pragma unroll
        for (int d = 1; d < D_ORIENT; ++d)
            if (sv[d] > bv) { bv = sv[d]; bd = d; }   // strict >  => smallest d on tie
        s_d = bd;
    }
    __syncthreads();

    const int CH = HW / NCHUNK;                       // 2048 floats per chunk
    const float4* __restrict__ src4 =
        (const float4*)(x + (size_t)bc * (D_ORIENT * HW) + (size_t)s_d * HW
                          + (size_t)chunk * CH);
    float4* __restrict__ dst4 =
        (float4*)(out + (size_t)bc * HW + (size_t)chunk * CH);
    #pragma unroll
    for (int i = tid; i < CH / 4; i += TB)            // 2 iterations
        dst4[i] = src4[i];
}

extern "C" void kernel_launch(void* const* d_in, const int* in_sizes, int n_in,
                              void* d_out, int out_size, void* d_ws, size_t ws_size,
                              hipStream_t stream) {
    const float* x = (const float*)d_in[0];
    float* out = (float*)d_out;
    const int n_bc = out_size / HW;                   // B*C = 512
    const int n_slices = n_bc * D_ORIENT;             // 6144
    float* pval = (float*)d_ws;                       // 6144 floats of scratch

    k_slicemax<<<n_slices, TB, 0, stream>>>(x, pval);
    k_copy<<<n_bc * NCHUNK, TB, 0, stream>>>(x, pval, out);
}

// Round 3
// 526.128 us; speedup vs baseline: 1.0089x; 1.0089x over previous
//
#include <hip/hip_runtime.h>

#define D_ORIENT 12
#define HW 16384                     // 128*128
#define TB 512
#define F4S (HW / 4)                 // 4096 float4 per slice
#define ITERS (F4S / TB)             // 8 float4 per thread per slice

// One block per (b,c). Scans the 12 orientation slices, keeping the
// best-so-far slice entirely in registers (32 floats/thread), so the winning
// slice is never re-read from HBM. Strict '>' over ascending d == smallest d
// on ties == jnp.argmax first-occurrence semantics.
__global__ __launch_bounds__(TB, 4) void opool_fused(const float* __restrict__ x,
                                                     float* __restrict__ out) {
    const int bc  = blockIdx.x;
    const int tid = threadIdx.x;
    const float4* __restrict__ base = (const float4*)(x + (size_t)bc * (D_ORIENT * HW));

    __shared__ float s_wmax[TB / 64];
    __shared__ int   s_take;

    float4 best[ITERS];
    float  bestmax = -__builtin_inff();   // only meaningful on tid 0

    #pragma unroll 1
    for (int d = 0; d < D_ORIENT; ++d) {
        const float4* __restrict__ sp = base + d * F4S;

        float4 cur[ITERS];
        #pragma unroll
        for (int k = 0; k < ITERS; ++k) cur[k] = sp[tid + k * TB];

        float m = -__builtin_inff();
        #pragma unroll
        for (int k = 0; k < ITERS; ++k)
            m = fmaxf(m, fmaxf(fmaxf(cur[k].x, cur[k].y), fmaxf(cur[k].z, cur[k].w)));

        #pragma unroll
        for (int off = 32; off >= 1; off >>= 1)
            m = fmaxf(m, __shfl_down(m, off, 64));
        if ((tid & 63) == 0) s_wmax[tid >> 6] = m;
        __syncthreads();                       // also protects s_take of prev iter

        if (tid == 0) {
            float sm = s_wmax[0];
            #pragma unroll
            for (int w = 1; w < TB / 64; ++w) sm = fmaxf(sm, s_wmax[w]);
            s_take = (sm > bestmax);
            bestmax = fmaxf(bestmax, sm);
        }
        __syncthreads();

        if (s_take) {                          // block-uniform branch, no divergence
            #pragma unroll
            for (int k = 0; k < ITERS; ++k) best[k] = cur[k];
        }
    }

    float4* __restrict__ dst = (float4*)(out + (size_t)bc * HW);
    #pragma unroll
    for (int k = 0; k < ITERS; ++k) dst[tid + k * TB] = best[k];
}

extern "C" void kernel_launch(void* const* d_in, const int* in_sizes, int n_in,
                              void* d_out, int out_size, void* d_ws, size_t ws_size,
                              hipStream_t stream) {
    const float* x = (const float*)d_in[0];
    float* out = (float*)d_out;
    const int n_bc = out_size / HW;            // B*C = 512
    opool_fused<<<n_bc, TB, 0, stream>>>(x, out);
}